// Round 12
// baseline (283.944 us; speedup 1.0000x reference)
//
#include <hip/hip_runtime.h>
#include <hip/hip_bf16.h>

#define DD 256
#define KK 4
#define CSZ 1024
#define NROWS 16384
#define TM 64           // rows per block -> 256 blocks, 1 per CU
#define NTHR 1024       // 16 waves: 4 rt-groups x 4 seg-groups
#define TAU 0.5f
#define MAXC 256

typedef __attribute__((ext_vector_type(8))) short bf16x8;
typedef __attribute__((ext_vector_type(4))) float f32x4;

__device__ __forceinline__ short f2bf(float f) {
    __hip_bfloat16 h = __float2bfloat16(f);
    return (short)__builtin_bit_cast(unsigned short, h);
}
__device__ __forceinline__ unsigned long long enc_d(double d) {
    unsigned long long u = __double_as_longlong(d);
    return (u & 0x8000000000000000ull) ? ~u : (u | 0x8000000000000000ull);
}

// bf16 copy of codebook, same [k][c][d] layout
__global__ __launch_bounds__(256) void cb_tobf(const float* __restrict__ cb,
                                               short* __restrict__ hi) {
    long e = (long)blockIdx.x * 256 + threadIdx.x;   // over K*CS*D = 1,048,576
    hi[e] = f2bf(cb[e]);
}

// per-entry squared norms, wave-per-entry (coalesced)
__global__ __launch_bounds__(256) void cnorm_kernel(const float* __restrict__ cb,
                                                    double* __restrict__ cn_d,
                                                    float* __restrict__ cn_f) {
    int wv = threadIdx.x >> 6, l = threadIdx.x & 63;
    int e = blockIdx.x * 4 + wv;                     // grid 1024 -> 4096 entries
    float4 v = *(const float4*)(cb + (size_t)e * DD + l * 4);
    double s = (double)v.x * (double)v.x + (double)v.y * (double)v.y
             + (double)v.z * (double)v.z + (double)v.w * (double)v.w;
#pragma unroll
    for (int off = 32; off > 0; off >>= 1) s += __shfl_xor(s, off, 64);
    if (l == 0) { cn_d[e] = s; cn_f[e] = (float)s; }
}

#define LOADB(Bv, CNv, ct_) {                                         \
    const int cE_ = seg + (ct_) * 16 + l15;                           \
    const short* bp_ = cbhk + (size_t)cE_ * DD + q8;                  \
    _Pragma("unroll")                                                 \
    for (int kk = 0; kk < 8; ++kk)                                    \
        Bv[kk] = *(const bf16x8*)(bp_ + kk * 32);                     \
    CNv = cnfk[cE_]; }

// positive-float keys: dist > 0 here, so raw f32 bits compare as unsigned.
#define KUPD(dval) {                                                  \
    float dc_ = fmaxf((dval), 0.f);                                   \
    unsigned kx_ = (__builtin_bit_cast(unsigned, dc_) & 0xFFFFFC00u)  \
                   | (unsigned)cE_;                                   \
    unsigned mx_ = (b0[reg] > kx_) ? b0[reg] : kx_;                   \
    b0[reg] = (b0[reg] < kx_) ? b0[reg] : kx_;                        \
    b1[reg] = (b1[reg] < mx_) ? b1[reg] : mx_; }

#define TILE1(Bv, CNv, ct_) {                                         \
    f32x4 ac = {0.f,0.f,0.f,0.f};                                     \
    _Pragma("unroll")                                                 \
    for (int kk = 0; kk < 8; ++kk)                                    \
        ac = __builtin_amdgcn_mfma_f32_16x16x32_bf16(A[kk], Bv[kk], ac, 0,0,0); \
    const int cE_ = seg + (ct_) * 16 + l15;                           \
    _Pragma("unroll")                                                 \
    for (int reg = 0; reg < 4; ++reg) {                               \
        KUPD(fmaf(-2.f, ac[reg], CNv));                               \
    } }

__global__ __launch_bounds__(NTHR, 4) void rvq_kernel(const float* __restrict__ z,
                                                  const float* __restrict__ cb,
                                                  const short* __restrict__ cb_hi,
                                                  const double* __restrict__ cn_d,
                                                  const float* __restrict__ cn_f,
                                                  int* __restrict__ idx_ws,
                                                  float* __restrict__ out) {
    __shared__ double res_d[TM][DD + 1];             // 131.6 KB fp64 master residual
    __shared__ unsigned wrowmin[16][TM];
    __shared__ int cand[MAXC];
    __shared__ unsigned long long rowkey[2][TM];     // double-buffered per stage
    __shared__ int ncand;

    const int tid = threadIdx.x;                     // 0..1023
    const int l   = tid & 63;        // lane
    const int wv  = tid >> 6;        // wave 0..15
    const int rt  = wv & 3;          // row-tile group
    const int l15 = l & 15;
    const int q   = l >> 4;          // quarter 0..3
    const int q8  = q * 8;
    const int row0 = blockIdx.x * TM;
    const int seg  = (wv >> 2) * 256;  // this wave's 256-entry codebook segment
    const int qrow = tid >> 8;       // 0..3: row split for 1024-thread loops
    const int hd   = tid & 255;      // d index for 1024-thread loops

    // ---- init: z -> fp64 residual; rowkey/ncand ----
#pragma unroll
    for (int it = 0; it < TM / 4; ++it) {
        int r = it * 4 + qrow;
        res_d[r][hd] = (double)z[(size_t)(row0 + r) * DD + hd];
    }
    if (tid < TM) { rowkey[0][tid] = ~0ull; rowkey[1][tid] = ~0ull; }
    if (tid == 0) ncand = 0;
    __syncthreads();

    for (int k = 0; k < KK; ++k) {
        const int kb = k & 1;
        // ---- A fragments for ONE row-tile (row = rt*16 + l15) ----
        bf16x8 A[8];
#pragma unroll
        for (int kk = 0; kk < 8; ++kk) {
            const double* rp = &res_d[rt * 16 + l15][kk * 32 + q8];
#pragma unroll
            for (int j = 0; j < 8; ++j)
                A[kk][j] = f2bf((float)rp[j]);
        }

        // ---- MFMA scan over this wave's 256 entries (single-buffered; TLP hides) ----
        const short* __restrict__ cbhk = cb_hi + (size_t)k * CSZ * DD;
        const float* __restrict__ cnfk = cn_f + k * CSZ;
        unsigned b0[4], b1[4];
#pragma unroll
        for (int reg = 0; reg < 4; ++reg) { b0[reg] = ~0u; b1[reg] = ~0u; }

        {
            bf16x8 Bx[8];
            float cnX;
#pragma unroll 1
            for (int ct = 0; ct < 16; ++ct) {
                LOADB(Bx, cnX, ct);
                TILE1(Bx, cnX, ct);
            }
        }

        // ---- per-wave row mins (16-lane groups) ----
#pragma unroll
        for (int reg = 0; reg < 4; ++reg) {
            unsigned m = b0[reg];
            m = min(m, (unsigned)__shfl_xor((int)m, 1, 64));
            m = min(m, (unsigned)__shfl_xor((int)m, 2, 64));
            m = min(m, (unsigned)__shfl_xor((int)m, 4, 64));
            m = min(m, (unsigned)__shfl_xor((int)m, 8, 64));
            if (l15 == 0) wrowmin[wv][rt * 16 + q * 4 + reg] = m;
        }
        __syncthreads();                                   // B1

        // ---- capture: block min over the 4 seg-groups of this rt ----
#pragma unroll
        for (int reg = 0; reg < 4; ++reg) {
            const int row = rt * 16 + q * 4 + reg;
            unsigned rk = min(min(wrowmin[rt][row], wrowmin[rt + 4][row]),
                              min(wrowmin[rt + 8][row], wrowmin[rt + 12][row]));
            float thrf = __builtin_bit_cast(float, rk | 0x3FFu) + TAU;
            unsigned tkey = (__builtin_bit_cast(unsigned, thrf) & 0xFFFFFC00u) | 0x3FFu;
            if (b0[reg] <= tkey) {
                int sl = atomicAdd(&ncand, 1);
                if (sl < MAXC) cand[sl] = row | ((int)(b0[reg] & 0x3FFu) << 16);
            }
            if (b1[reg] <= tkey) {
                int sl = atomicAdd(&ncand, 1);
                if (sl < MAXC) cand[sl] = row | ((int)(b1[reg] & 0x3FFu) << 16);
            }
        }
        __syncthreads();                                   // B2

        // ---- fp64 refine: 64 16-lane groups, one candidate each, strided ----
        const int nc = (ncand < MAXC) ? ncand : MAXC;
        const float* __restrict__ cbk   = cb + (size_t)k * CSZ * DD;
        const double* __restrict__ cndk = cn_d + k * CSZ;
        const int g = tid >> 4;                            // group 0..63
        for (int i = g; i < nc; i += 64) {
            int rc  = cand[i];
            int row = rc & 0xFFFF;
            int c   = rc >> 16;
            const float* crow = cbk + (size_t)c * DD;
            double p = 0.0;
#pragma unroll
            for (int ii = 0; ii < 16; ++ii)
                p += res_d[row][ii * 16 + l15] * (double)crow[ii * 16 + l15];
            p += __shfl_xor(p, 1, 64);
            p += __shfl_xor(p, 2, 64);
            p += __shfl_xor(p, 4, 64);
            p += __shfl_xor(p, 8, 64);
            if (l15 == 0) {
                double dist = cndk[c] - 2.0 * p;
                unsigned long long key =
                    (enc_d(dist) & 0xFFFFFFFFFFFFFC00ull) | (unsigned long long)c;
                atomicMin(&rowkey[kb][row], key);
            }
        }
        __syncthreads();                                   // B3

        // ---- idx write + residual update + next-stage resets ----
        if (tid < TM)
            idx_ws[(size_t)(row0 + tid) * KK + k] = (int)(rowkey[kb][tid] & 1023ull);
#pragma unroll
        for (int it = 0; it < TM / 4; ++it) {
            int r = it * 4 + qrow;
            int c = (int)(rowkey[kb][r] & 1023ull);        // broadcast LDS read
            double qv = (double)cbk[(size_t)c * DD + hd];
            double rd = res_d[r][hd];
            double s  = qv - rd;       // stop_gradient(q - residual)
            double zq = rd + s;        // z_q value
            res_d[r][hd] = rd - zq;    // next residual
        }
        if (tid < TM) rowkey[kb ^ 1][tid] = ~0ull;
        if (tid == 0) ncand = 0;
        __syncthreads();                                   // B4
    }

    // ---- z_q_final = z - residual_final (f32 out, chunk 0) ----
#pragma unroll
    for (int it = 0; it < TM / 4; ++it) {
        int r = it * 4 + qrow;
        size_t o = (size_t)(row0 + r) * DD + hd;
        out[o] = (float)((double)z[o] - res_d[r][hd]);
    }
}

// index writer: chunk 1, float32 values
__global__ __launch_bounds__(256) void idx_write(const int* __restrict__ idx_ws,
                                                 float* __restrict__ out) {
    int i = blockIdx.x * 256 + threadIdx.x;          // < NROWS*KK = 65536
    out[(long)NROWS * DD + i] = (float)idx_ws[i];
}

extern "C" void kernel_launch(void* const* d_in, const int* in_sizes, int n_in,
                              void* d_out, int out_size, void* d_ws, size_t ws_size,
                              hipStream_t stream) {
    (void)in_sizes; (void)n_in; (void)out_size; (void)ws_size;
    const float* z  = (const float*)d_in[0];
    const float* cb = (const float*)d_in[1];

    char* ws = (char*)d_ws;
    short*  cb_hi = (short*)ws;                                   // 2 MB
    double* cn_d  = (double*)(ws + (size_t)2 * 1024 * 1024);      // 32 KB
    float*  cn_f  = (float*)(ws + (size_t)2 * 1024 * 1024 + 32 * 1024);  // 16 KB
    int*    idxs  = (int*)(ws + (size_t)2 * 1024 * 1024 + 48 * 1024);    // 256 KB
    float* out = (float*)d_out;

    cb_tobf<<<(KK * CSZ * DD) / 256, 256, 0, stream>>>(cb, cb_hi);
    cnorm_kernel<<<(KK * CSZ) / 4, 256, 0, stream>>>(cb, cn_d, cn_f);
    rvq_kernel<<<NROWS / TM, NTHR, 0, stream>>>(z, cb, cb_hi, cn_d, cn_f, idxs, out);
    idx_write<<<(NROWS * KK) / 256, 256, 0, stream>>>(idxs, out);
}

// Round 13
// 150.818 us; speedup vs baseline: 1.8827x; 1.8827x over previous
//
#include <hip/hip_runtime.h>
#include <hip/hip_bf16.h>

#define DD 256
#define KK 4
#define CSZ 1024
#define NROWS 16384
#define TM 64           // rows per block -> 256 blocks, 1 per CU
#define TAU 0.5f
#define MAXC 192

typedef __attribute__((ext_vector_type(8))) short bf16x8;
typedef __attribute__((ext_vector_type(4))) float f32x4;

__device__ __forceinline__ short f2bf(float f) {
    __hip_bfloat16 h = __float2bfloat16(f);
    return (short)__builtin_bit_cast(unsigned short, h);
}
__device__ __forceinline__ unsigned long long enc_d(double d) {
    unsigned long long u = __double_as_longlong(d);
    return (u & 0x8000000000000000ull) ? ~u : (u | 0x8000000000000000ull);
}

// pack codebook into MFMA B-fragment order:
// packed[((k*64+ctg)*8+kk)*64 + lane][0..7] = bf16(cb[k][ctg*16+(lane&15)][kk*32+(lane>>4)*8 + j])
// -> every scan load is one coalesced 1KB stream.
__global__ __launch_bounds__(256) void cb_pack(const float* __restrict__ cb,
                                               short* __restrict__ packed) {
    int idx  = blockIdx.x * 256 + threadIdx.x;       // over 4*64*8*64 = 131072
    int lane = idx & 63;
    int kk   = (idx >> 6) & 7;
    int tg   = idx >> 9;                             // k*64 + ctg
    int k    = tg >> 6;
    int ctg  = tg & 63;
    int c    = ctg * 16 + (lane & 15);
    int d0   = kk * 32 + (lane >> 4) * 8;
    const float* src = cb + ((size_t)(k * CSZ + c)) * DD + d0;
    short* dst = packed + (size_t)idx * 8;
#pragma unroll
    for (int j = 0; j < 8; ++j) dst[j] = f2bf(src[j]);
}

// per-entry squared norms, wave-per-entry (coalesced)
__global__ __launch_bounds__(256) void cnorm_kernel(const float* __restrict__ cb,
                                                    double* __restrict__ cn_d,
                                                    float* __restrict__ cn_f) {
    int wv = threadIdx.x >> 6, l = threadIdx.x & 63;
    int e = blockIdx.x * 4 + wv;                     // grid 1024 -> 4096 entries
    float4 v = *(const float4*)(cb + (size_t)e * DD + l * 4);
    double s = (double)v.x * (double)v.x + (double)v.y * (double)v.y
             + (double)v.z * (double)v.z + (double)v.w * (double)v.w;
#pragma unroll
    for (int off = 32; off > 0; off >>= 1) s += __shfl_xor(s, off, 64);
    if (l == 0) { cn_d[e] = s; cn_f[e] = (float)s; }
}

// coalesced fragment load from packed codebook
#define LOADB(Bv, CNv, ct_) {                                         \
    const short* bp_ = pkk + (size_t)((seg >> 4) + (ct_)) * 4096 + l * 8; \
    _Pragma("unroll")                                                 \
    for (int kk = 0; kk < 8; ++kk)                                    \
        Bv[kk] = *(const bf16x8*)(bp_ + kk * 512);                    \
    CNv = cnfk[seg + (ct_) * 16 + l15]; }

// positive-float keys: dist > 0 here, so raw f32 bits compare as unsigned.
#define KUPD(rt_, dval) {                                             \
    float dc_ = fmaxf((dval), 0.f);                                   \
    unsigned kx_ = (__builtin_bit_cast(unsigned, dc_) & 0xFFFFFC00u)  \
                   | (unsigned)cE_;                                   \
    unsigned mx_ = (b0[rt_][reg] > kx_) ? b0[rt_][reg] : kx_;         \
    b0[rt_][reg] = (b0[rt_][reg] < kx_) ? b0[rt_][reg] : kx_;         \
    b1[rt_][reg] = (b1[rt_][reg] < mx_) ? b1[rt_][reg] : mx_; }

#define TILE4(Bv, CNv, ct_) {                                         \
    f32x4 ac0 = {0.f,0.f,0.f,0.f}, ac1 = {0.f,0.f,0.f,0.f};           \
    f32x4 ac2 = {0.f,0.f,0.f,0.f}, ac3 = {0.f,0.f,0.f,0.f};           \
    _Pragma("unroll")                                                 \
    for (int kk = 0; kk < 8; ++kk) {                                  \
        ac0 = __builtin_amdgcn_mfma_f32_16x16x32_bf16(A[0][kk], Bv[kk], ac0, 0,0,0); \
        ac1 = __builtin_amdgcn_mfma_f32_16x16x32_bf16(A[1][kk], Bv[kk], ac1, 0,0,0); \
        ac2 = __builtin_amdgcn_mfma_f32_16x16x32_bf16(A[2][kk], Bv[kk], ac2, 0,0,0); \
        ac3 = __builtin_amdgcn_mfma_f32_16x16x32_bf16(A[3][kk], Bv[kk], ac3, 0,0,0); \
    }                                                                 \
    const int cE_ = seg + (ct_) * 16 + l15;                           \
    _Pragma("unroll")                                                 \
    for (int reg = 0; reg < 4; ++reg) {                               \
        KUPD(0, fmaf(-2.f, ac0[reg], CNv));                           \
        KUPD(1, fmaf(-2.f, ac1[reg], CNv));                           \
        KUPD(2, fmaf(-2.f, ac2[reg], CNv));                           \
        KUPD(3, fmaf(-2.f, ac3[reg], CNv));                           \
    } }

__global__ __launch_bounds__(256, 1) void rvq_kernel(const float* __restrict__ z,
                                                  const float* __restrict__ cb,
                                                  const short* __restrict__ packed,
                                                  const double* __restrict__ cn_d,
                                                  const float* __restrict__ cn_f,
                                                  int* __restrict__ idx_ws,
                                                  float* __restrict__ out) {
    __shared__ double res_d[TM][DD + 1];             // 131.6 KB fp64 master residual
    __shared__ unsigned wrowmin[4][TM];
    __shared__ int cand[MAXC];
    __shared__ unsigned long long rowkey[2][TM];     // double-buffered per stage
    __shared__ int ncand;

    const int tid = threadIdx.x;
    const int l   = tid & 63;        // lane
    const int wv  = tid >> 6;        // wave 0..3
    const int l15 = l & 15;
    const int q   = l >> 4;          // quarter 0..3
    const int q8  = q * 8;
    const int row0 = blockIdx.x * TM;
    const int seg  = wv * 256;       // this wave's codebook segment

    // ---- init: z -> fp64 residual; rowkey/ncand ----
#pragma unroll 4
    for (int r = 0; r < TM; ++r)
        res_d[r][tid] = (double)z[(size_t)(row0 + r) * DD + tid];
    if (tid < TM) { rowkey[0][tid] = ~0ull; rowkey[1][tid] = ~0ull; }
    if (tid == 0) ncand = 0;
    __syncthreads();

    for (int k = 0; k < KK; ++k) {
        const int kb = k & 1;
        // ---- A fragments for 4 row-tiles (row = rt*16 + l15) ----
        bf16x8 A[4][8];
#pragma unroll
        for (int rt = 0; rt < 4; ++rt)
#pragma unroll
            for (int kk = 0; kk < 8; ++kk) {
                const double* rp = &res_d[rt * 16 + l15][kk * 32 + q8];
#pragma unroll
                for (int j = 0; j < 8; ++j)
                    A[rt][kk][j] = f2bf((float)rp[j]);
            }

        // ---- MFMA scan over this wave's 256 entries, double-buffered ----
        const short* __restrict__ pkk  = packed + (size_t)k * CSZ * DD;
        const float* __restrict__ cnfk = cn_f + k * CSZ;
        unsigned b0[4][4], b1[4][4];
#pragma unroll
        for (int rt = 0; rt < 4; ++rt)
#pragma unroll
            for (int reg = 0; reg < 4; ++reg) { b0[rt][reg] = ~0u; b1[rt][reg] = ~0u; }

        bf16x8 Bp[8], Bq[8];
        float cnP, cnQ;
        LOADB(Bp, cnP, 0);
        for (int ct2 = 0; ct2 < 8; ++ct2) {
            LOADB(Bq, cnQ, 2 * ct2 + 1);
            TILE4(Bp, cnP, 2 * ct2);
            if (ct2 < 7) LOADB(Bp, cnP, 2 * ct2 + 2);
            TILE4(Bq, cnQ, 2 * ct2 + 1);
        }

        // ---- per-wave row mins (16-lane groups) ----
#pragma unroll
        for (int rt = 0; rt < 4; ++rt)
#pragma unroll
            for (int reg = 0; reg < 4; ++reg) {
                unsigned m = b0[rt][reg];
                m = min(m, (unsigned)__shfl_xor((int)m, 1, 64));
                m = min(m, (unsigned)__shfl_xor((int)m, 2, 64));
                m = min(m, (unsigned)__shfl_xor((int)m, 4, 64));
                m = min(m, (unsigned)__shfl_xor((int)m, 8, 64));
                if (l15 == 0) wrowmin[wv][rt * 16 + q * 4 + reg] = m;
            }
        __syncthreads();

        // ---- capture: block min inline; best+2nd per lane-slot within TAU ----
#pragma unroll
        for (int rt = 0; rt < 4; ++rt)
#pragma unroll
            for (int reg = 0; reg < 4; ++reg) {
                const int row = rt * 16 + q * 4 + reg;
                unsigned rk = min(min(wrowmin[0][row], wrowmin[1][row]),
                                  min(wrowmin[2][row], wrowmin[3][row]));
                float thrf = __builtin_bit_cast(float, rk | 0x3FFu) + TAU;
                unsigned tkey = (__builtin_bit_cast(unsigned, thrf) & 0xFFFFFC00u) | 0x3FFu;
                if (b0[rt][reg] <= tkey) {
                    int sl = atomicAdd(&ncand, 1);
                    if (sl < MAXC) cand[sl] = row | ((int)(b0[rt][reg] & 0x3FFu) << 16);
                }
                if (b1[rt][reg] <= tkey) {
                    int sl = atomicAdd(&ncand, 1);
                    if (sl < MAXC) cand[sl] = row | ((int)(b1[rt][reg] & 0x3FFu) << 16);
                }
            }
        __syncthreads();

        // ---- fp64 refine: 16-lane groups, one candidate each, strided ----
        const int nc = (ncand < MAXC) ? ncand : MAXC;
        const float* __restrict__ cbk   = cb + (size_t)k * CSZ * DD;
        const double* __restrict__ cndk = cn_d + k * CSZ;
        const int g = tid >> 4;                      // group 0..15
        for (int i = g; i < nc; i += 16) {
            int rc  = cand[i];
            int row = rc & 0xFFFF;
            int c   = rc >> 16;
            const float* crow = cbk + (size_t)c * DD;
            double p = 0.0;
#pragma unroll
            for (int ii = 0; ii < 16; ++ii)
                p += res_d[row][ii * 16 + l15] * (double)crow[ii * 16 + l15];
            p += __shfl_xor(p, 1, 64);
            p += __shfl_xor(p, 2, 64);
            p += __shfl_xor(p, 4, 64);
            p += __shfl_xor(p, 8, 64);
            if (l15 == 0) {
                double dist = cndk[c] - 2.0 * p;
                unsigned long long key =
                    (enc_d(dist) & 0xFFFFFFFFFFFFFC00ull) | (unsigned long long)c;
                atomicMin(&rowkey[kb][row], key);
            }
        }
        __syncthreads();

        // ---- idx write + residual update + next-stage resets ----
        if (tid < TM)
            idx_ws[(size_t)(row0 + tid) * KK + k] = (int)(rowkey[kb][tid] & 1023ull);
#pragma unroll 4
        for (int r = 0; r < TM; ++r) {
            int c = (int)(rowkey[kb][r] & 1023ull);  // broadcast LDS read
            double qv = (double)cbk[(size_t)c * DD + tid];
            double rd = res_d[r][tid];
            double s  = qv - rd;       // stop_gradient(q - residual)
            double zq = rd + s;        // z_q value
            res_d[r][tid] = rd - zq;   // next residual
        }
        if (tid < TM) rowkey[kb ^ 1][tid] = ~0ull;
        if (tid == 0) ncand = 0;
        __syncthreads();
    }

    // ---- z_q_final = z - residual_final (f32 out, chunk 0) ----
#pragma unroll 4
    for (int r = 0; r < TM; ++r) {
        size_t o = (size_t)(row0 + r) * DD + tid;
        out[o] = (float)((double)z[o] - res_d[r][tid]);
    }
}

// index writer: chunk 1, float32 values
__global__ __launch_bounds__(256) void idx_write(const int* __restrict__ idx_ws,
                                                 float* __restrict__ out) {
    int i = blockIdx.x * 256 + threadIdx.x;          // < NROWS*KK = 65536
    out[(long)NROWS * DD + i] = (float)idx_ws[i];
}

extern "C" void kernel_launch(void* const* d_in, const int* in_sizes, int n_in,
                              void* d_out, int out_size, void* d_ws, size_t ws_size,
                              hipStream_t stream) {
    (void)in_sizes; (void)n_in; (void)out_size; (void)ws_size;
    const float* z  = (const float*)d_in[0];
    const float* cb = (const float*)d_in[1];

    char* ws = (char*)d_ws;
    short*  packed = (short*)ws;                                  // 2 MB
    double* cn_d  = (double*)(ws + (size_t)2 * 1024 * 1024);      // 32 KB
    float*  cn_f  = (float*)(ws + (size_t)2 * 1024 * 1024 + 32 * 1024);  // 16 KB
    int*    idxs  = (int*)(ws + (size_t)2 * 1024 * 1024 + 48 * 1024);    // 256 KB
    float* out = (float*)d_out;

    cb_pack<<<(KK * 64 * 8 * 64) / 256, 256, 0, stream>>>(cb, packed);
    cnorm_kernel<<<(KK * CSZ) / 4, 256, 0, stream>>>(cb, cn_d, cn_f);
    rvq_kernel<<<NROWS / TM, 256, 0, stream>>>(z, cb, packed, cn_d, cn_f, idxs, out);
    idx_write<<<(NROWS * KK) / 256, 256, 0, stream>>>(idxs, out);
}

// Round 14
// 104.215 us; speedup vs baseline: 2.7246x; 1.4472x over previous
//
#include <hip/hip_runtime.h>
#include <hip/hip_bf16.h>

#define DD 256
#define KK 4
#define CSZ 1024
#define NROWS 16384
#define TM 64           // rows per block -> 256 blocks, 1 per CU
#define NTHR 512        // 8 waves: 2 row-halves x 4 segments
#define TAU 0.5f
#define MAXC 192

typedef __attribute__((ext_vector_type(8))) short bf16x8;
typedef __attribute__((ext_vector_type(4))) float f32x4;

__device__ __forceinline__ short f2bf(float f) {
    __hip_bfloat16 h = __float2bfloat16(f);
    return (short)__builtin_bit_cast(unsigned short, h);
}
__device__ __forceinline__ unsigned long long enc_d(double d) {
    unsigned long long u = __double_as_longlong(d);
    return (u & 0x8000000000000000ull) ? ~u : (u | 0x8000000000000000ull);
}

// pack codebook into MFMA B-fragment order (one coalesced 1KB stream per load)
__global__ __launch_bounds__(256) void cb_pack(const float* __restrict__ cb,
                                               short* __restrict__ packed) {
    int idx  = blockIdx.x * 256 + threadIdx.x;       // over 4*64*8*64 = 131072
    int lane = idx & 63;
    int kk   = (idx >> 6) & 7;
    int tg   = idx >> 9;                             // k*64 + ctg
    int k    = tg >> 6;
    int ctg  = tg & 63;
    int c    = ctg * 16 + (lane & 15);
    int d0   = kk * 32 + (lane >> 4) * 8;
    const float* src = cb + ((size_t)(k * CSZ + c)) * DD + d0;
    short* dst = packed + (size_t)idx * 8;
#pragma unroll
    for (int j = 0; j < 8; ++j) dst[j] = f2bf(src[j]);
}

// per-entry squared norms, wave-per-entry (coalesced)
__global__ __launch_bounds__(256) void cnorm_kernel(const float* __restrict__ cb,
                                                    double* __restrict__ cn_d,
                                                    float* __restrict__ cn_f) {
    int wv = threadIdx.x >> 6, l = threadIdx.x & 63;
    int e = blockIdx.x * 4 + wv;                     // grid 1024 -> 4096 entries
    float4 v = *(const float4*)(cb + (size_t)e * DD + l * 4);
    double s = (double)v.x * (double)v.x + (double)v.y * (double)v.y
             + (double)v.z * (double)v.z + (double)v.w * (double)v.w;
#pragma unroll
    for (int off = 32; off > 0; off >>= 1) s += __shfl_xor(s, off, 64);
    if (l == 0) { cn_d[e] = s; cn_f[e] = (float)s; }
}

// coalesced fragment load from packed codebook
#define LOADB(Bv, CNv, ct_) {                                         \
    const short* bp_ = pkk + (size_t)((seg >> 4) + (ct_)) * 4096 + l * 8; \
    _Pragma("unroll")                                                 \
    for (int kk = 0; kk < 8; ++kk)                                    \
        Bv[kk] = *(const bf16x8*)(bp_ + kk * 512);                    \
    CNv = cnfk[seg + (ct_) * 16 + l15]; }

// positive-float keys: dist > 0 here, so raw f32 bits compare as unsigned.
#define KUPD(rt_, dval) {                                             \
    float dc_ = fmaxf((dval), 0.f);                                   \
    unsigned kx_ = (__builtin_bit_cast(unsigned, dc_) & 0xFFFFFC00u)  \
                   | (unsigned)cE_;                                   \
    unsigned mx_ = (b0[rt_][reg] > kx_) ? b0[rt_][reg] : kx_;         \
    b0[rt_][reg] = (b0[rt_][reg] < kx_) ? b0[rt_][reg] : kx_;         \
    b1[rt_][reg] = (b1[rt_][reg] < mx_) ? b1[rt_][reg] : mx_; }

#define TILE2(Bv, CNv, ct_) {                                         \
    f32x4 ac0 = {0.f,0.f,0.f,0.f}, ac1 = {0.f,0.f,0.f,0.f};           \
    _Pragma("unroll")                                                 \
    for (int kk = 0; kk < 8; ++kk) {                                  \
        ac0 = __builtin_amdgcn_mfma_f32_16x16x32_bf16(A[0][kk], Bv[kk], ac0, 0,0,0); \
        ac1 = __builtin_amdgcn_mfma_f32_16x16x32_bf16(A[1][kk], Bv[kk], ac1, 0,0,0); \
    }                                                                 \
    const int cE_ = seg + (ct_) * 16 + l15;                           \
    _Pragma("unroll")                                                 \
    for (int reg = 0; reg < 4; ++reg) {                               \
        KUPD(0, fmaf(-2.f, ac0[reg], CNv));                           \
        KUPD(1, fmaf(-2.f, ac1[reg], CNv));                           \
    } }

__global__ __launch_bounds__(NTHR, 2) void rvq_kernel(const float* __restrict__ z,
                                                  const float* __restrict__ cb,
                                                  const short* __restrict__ packed,
                                                  const double* __restrict__ cn_d,
                                                  const float* __restrict__ cn_f,
                                                  int* __restrict__ idx_ws,
                                                  float* __restrict__ out) {
    __shared__ double res_d[TM][DD + 1];             // 131.6 KB fp64 master residual
    __shared__ unsigned wrowmin[8][TM];
    __shared__ int cand[MAXC];
    __shared__ unsigned long long rowkey[2][TM];     // double-buffered per stage
    __shared__ int ncand;

    const int tid = threadIdx.x;                     // 0..511
    const int l   = tid & 63;        // lane
    const int wv  = tid >> 6;        // wave 0..7
    const int rtp = wv & 1;          // row-half: rows [32*rtp, 32*rtp+32)
    const int l15 = l & 15;
    const int q   = l >> 4;          // quarter 0..3
    const int q8  = q * 8;
    const int row0 = blockIdx.x * TM;
    const int seg  = (wv >> 1) * 256;  // this wave's 256-entry codebook segment
    const int hrow = tid >> 8;       // 0/1: row split for 512-thread loops
    const int hd   = tid & 255;      // d index for 512-thread loops

    // ---- init: z -> fp64 residual; rowkey/ncand ----
#pragma unroll 4
    for (int it = 0; it < TM / 2; ++it) {
        int r = it * 2 + hrow;
        res_d[r][hd] = (double)z[(size_t)(row0 + r) * DD + hd];
    }
    if (tid < TM) { rowkey[0][tid] = ~0ull; rowkey[1][tid] = ~0ull; }
    if (tid == 0) ncand = 0;
    __syncthreads();

    for (int k = 0; k < KK; ++k) {
        const int kb = k & 1;
        // ---- A fragments for this wave's 2 row-tiles (rows 32*rtp + rtl*16 + l15) ----
        bf16x8 A[2][8];
#pragma unroll
        for (int rtl = 0; rtl < 2; ++rtl)
#pragma unroll
            for (int kk = 0; kk < 8; ++kk) {
                const double* rp = &res_d[rtp * 32 + rtl * 16 + l15][kk * 32 + q8];
#pragma unroll
                for (int j = 0; j < 8; ++j)
                    A[rtl][kk][j] = f2bf((float)rp[j]);
            }

        // ---- MFMA scan over this wave's 256 entries, double-buffered ----
        const short* __restrict__ pkk  = packed + (size_t)k * CSZ * DD;
        const float* __restrict__ cnfk = cn_f + k * CSZ;
        unsigned b0[2][4], b1[2][4];
#pragma unroll
        for (int rtl = 0; rtl < 2; ++rtl)
#pragma unroll
            for (int reg = 0; reg < 4; ++reg) { b0[rtl][reg] = ~0u; b1[rtl][reg] = ~0u; }

        bf16x8 Bp[8], Bq[8];
        float cnP, cnQ;
        LOADB(Bp, cnP, 0);
        for (int ct2 = 0; ct2 < 8; ++ct2) {
            LOADB(Bq, cnQ, 2 * ct2 + 1);
            TILE2(Bp, cnP, 2 * ct2);
            if (ct2 < 7) LOADB(Bp, cnP, 2 * ct2 + 2);
            TILE2(Bq, cnQ, 2 * ct2 + 1);
        }

        // ---- per-wave row mins (16-lane groups) ----
#pragma unroll
        for (int rtl = 0; rtl < 2; ++rtl)
#pragma unroll
            for (int reg = 0; reg < 4; ++reg) {
                unsigned m = b0[rtl][reg];
                m = min(m, (unsigned)__shfl_xor((int)m, 1, 64));
                m = min(m, (unsigned)__shfl_xor((int)m, 2, 64));
                m = min(m, (unsigned)__shfl_xor((int)m, 4, 64));
                m = min(m, (unsigned)__shfl_xor((int)m, 8, 64));
                if (l15 == 0) wrowmin[wv][rtp * 32 + rtl * 16 + q * 4 + reg] = m;
            }
        __syncthreads();                                   // B1

        // ---- capture: block min over the 4 seg-waves of this row-half ----
#pragma unroll
        for (int rtl = 0; rtl < 2; ++rtl)
#pragma unroll
            for (int reg = 0; reg < 4; ++reg) {
                const int row = rtp * 32 + rtl * 16 + q * 4 + reg;
                unsigned rk = min(min(wrowmin[rtp][row], wrowmin[rtp + 2][row]),
                                  min(wrowmin[rtp + 4][row], wrowmin[rtp + 6][row]));
                float thrf = __builtin_bit_cast(float, rk | 0x3FFu) + TAU;
                unsigned tkey = (__builtin_bit_cast(unsigned, thrf) & 0xFFFFFC00u) | 0x3FFu;
                if (b0[rtl][reg] <= tkey) {
                    int sl = atomicAdd(&ncand, 1);
                    if (sl < MAXC) cand[sl] = row | ((int)(b0[rtl][reg] & 0x3FFu) << 16);
                }
                if (b1[rtl][reg] <= tkey) {
                    int sl = atomicAdd(&ncand, 1);
                    if (sl < MAXC) cand[sl] = row | ((int)(b1[rtl][reg] & 0x3FFu) << 16);
                }
            }
        __syncthreads();                                   // B2

        // ---- fp64 refine: 32 16-lane groups, one candidate each, strided ----
        const int nc = (ncand < MAXC) ? ncand : MAXC;
        const float* __restrict__ cbk   = cb + (size_t)k * CSZ * DD;
        const double* __restrict__ cndk = cn_d + k * CSZ;
        const int g = tid >> 4;                            // group 0..31
        for (int i = g; i < nc; i += 32) {
            int rc  = cand[i];
            int row = rc & 0xFFFF;
            int c   = rc >> 16;
            const float* crow = cbk + (size_t)c * DD;
            double p = 0.0;
#pragma unroll
            for (int ii = 0; ii < 16; ++ii)
                p += res_d[row][ii * 16 + l15] * (double)crow[ii * 16 + l15];
            p += __shfl_xor(p, 1, 64);
            p += __shfl_xor(p, 2, 64);
            p += __shfl_xor(p, 4, 64);
            p += __shfl_xor(p, 8, 64);
            if (l15 == 0) {
                double dist = cndk[c] - 2.0 * p;
                unsigned long long key =
                    (enc_d(dist) & 0xFFFFFFFFFFFFFC00ull) | (unsigned long long)c;
                atomicMin(&rowkey[kb][row], key);
            }
        }
        __syncthreads();                                   // B3

        // ---- idx write + residual update + next-stage resets ----
        if (tid < TM)
            idx_ws[(size_t)(row0 + tid) * KK + k] = (int)(rowkey[kb][tid] & 1023ull);
#pragma unroll 4
        for (int it = 0; it < TM / 2; ++it) {
            int r = it * 2 + hrow;
            int c = (int)(rowkey[kb][r] & 1023ull);        // broadcast LDS read
            double qv = (double)cbk[(size_t)c * DD + hd];
            double rd = res_d[r][hd];
            double s  = qv - rd;       // stop_gradient(q - residual)
            double zq = rd + s;        // z_q value
            res_d[r][hd] = rd - zq;    // next residual
        }
        if (tid < TM) rowkey[kb ^ 1][tid] = ~0ull;
        if (tid == 0) ncand = 0;
        __syncthreads();                                   // B4
    }

    // ---- z_q_final = z - residual_final (f32 out, chunk 0) ----
#pragma unroll 4
    for (int it = 0; it < TM / 2; ++it) {
        int r = it * 2 + hrow;
        size_t o = (size_t)(row0 + r) * DD + hd;
        out[o] = (float)((double)z[o] - res_d[r][hd]);
    }
}

// index writer: chunk 1, float32 values
__global__ __launch_bounds__(256) void idx_write(const int* __restrict__ idx_ws,
                                                 float* __restrict__ out) {
    int i = blockIdx.x * 256 + threadIdx.x;          // < NROWS*KK = 65536
    out[(long)NROWS * DD + i] = (float)idx_ws[i];
}

extern "C" void kernel_launch(void* const* d_in, const int* in_sizes, int n_in,
                              void* d_out, int out_size, void* d_ws, size_t ws_size,
                              hipStream_t stream) {
    (void)in_sizes; (void)n_in; (void)out_size; (void)ws_size;
    const float* z  = (const float*)d_in[0];
    const float* cb = (const float*)d_in[1];

    char* ws = (char*)d_ws;
    short*  packed = (short*)ws;                                  // 2 MB
    double* cn_d  = (double*)(ws + (size_t)2 * 1024 * 1024);      // 32 KB
    float*  cn_f  = (float*)(ws + (size_t)2 * 1024 * 1024 + 32 * 1024);  // 16 KB
    int*    idxs  = (int*)(ws + (size_t)2 * 1024 * 1024 + 48 * 1024);    // 256 KB
    float* out = (float*)d_out;

    cb_pack<<<(KK * 64 * 8 * 64) / 256, 256, 0, stream>>>(cb, packed);
    cnorm_kernel<<<(KK * CSZ) / 4, 256, 0, stream>>>(cb, cn_d, cn_f);
    rvq_kernel<<<NROWS / TM, NTHR, 0, stream>>>(z, cb, packed, cn_d, cn_f, idxs, out);
    idx_write<<<(NROWS * KK) / 256, 256, 0, stream>>>(idxs, out);
}